// Round 1
// baseline (1006.427 us; speedup 1.0000x reference)
//
#include <hip/hip_runtime.h>

// GraphPooling: voxel-grid pooling.
//  inputs: x[N,64] f32, pos[N,3] f32, edge_index[E,2] i32, batch[N] i32
//  outputs (concat, all read back as f32): pooled_x[M,64], pos_mean[M,3],
//    ei_out[Ed+M,2], new_batch[M]
// Keyspace: key = ((b*s0+qx)*s1+qy)*s2+qz < 16*32*32*32 = 524288.

#define KSP 524288
#define SCAN_BLOCK 256
#define SCAN_ITEMS 16
#define SCAN_CHUNK 4096            // SCAN_BLOCK * SCAN_ITEMS
#define NCHUNK (KSP / SCAN_CHUNK)  // 128

// ws header slots (u32)
// [0..2] = max qpos per axis, [3] = M, [4] = validE, [5] = Ed

__device__ __forceinline__ unsigned encF(float f) {
  unsigned u = __float_as_uint(f);
  return (u & 0x80000000u) ? ~u : (u | 0x80000000u);
}
__device__ __forceinline__ float decF(unsigned u) {
  return (u & 0x80000000u) ? __uint_as_float(u & 0x7FFFFFFFu)
                           : __uint_as_float(~u);
}

// ---- per-point: max of quantized coords (block-reduced) ----
__global__ void k_qmax(const float* __restrict__ pos, unsigned* hdr, int N) {
  __shared__ unsigned sm[3];
  if (threadIdx.x < 3) sm[threadIdx.x] = 0;
  __syncthreads();
  int i = blockIdx.x * blockDim.x + threadIdx.x;
  if (i < N) {
    int q0 = (int)floorf(pos[3 * i + 0] * 0.25f);
    int q1 = (int)floorf(pos[3 * i + 1] * 0.25f);
    int q2 = (int)floorf(pos[3 * i + 2] * 0.25f);
    atomicMax(&sm[0], (unsigned)q0);
    atomicMax(&sm[1], (unsigned)q1);
    atomicMax(&sm[2], (unsigned)q2);
  }
  __syncthreads();
  if (threadIdx.x < 3) atomicMax(&hdr[threadIdx.x], sm[threadIdx.x]);
}

// ---- per-point: linearized voxel key + histogram ----
__global__ void k_keys(const float* __restrict__ pos, const int* __restrict__ batch,
                       const unsigned* __restrict__ hdr, unsigned* __restrict__ key,
                       unsigned* __restrict__ cnt, int N) {
  int i = blockIdx.x * blockDim.x + threadIdx.x;
  if (i >= N) return;
  unsigned s0 = hdr[0] + 1, s1 = hdr[1] + 1, s2 = hdr[2] + 1;
  unsigned q0 = (unsigned)(int)floorf(pos[3 * i + 0] * 0.25f);
  unsigned q1 = (unsigned)(int)floorf(pos[3 * i + 1] * 0.25f);
  unsigned q2 = (unsigned)(int)floorf(pos[3 * i + 2] * 0.25f);
  unsigned k = (((unsigned)batch[i] * s0 + q0) * s1 + q1) * s2 + q2;
  key[i] = k;
  atomicAdd(&cnt[k], 1u);
}

// ---- generic 3-phase exclusive scan over KSP entries ----
__global__ void scanA(const unsigned* __restrict__ in, unsigned* __restrict__ out,
                      unsigned* __restrict__ chunkSums, int n, int presence) {
  __shared__ unsigned lds[SCAN_BLOCK];
  int base = blockIdx.x * SCAN_CHUNK;
  int tbase = base + threadIdx.x * SCAN_ITEMS;
  unsigned vals[SCAN_ITEMS];
  unsigned sum = 0;
  for (int i = 0; i < SCAN_ITEMS; ++i) {
    unsigned v = 0;
    int idx = tbase + i;
    if (idx < n) { v = in[idx]; if (presence) v = v ? 1u : 0u; }
    vals[i] = sum;
    sum += v;
  }
  lds[threadIdx.x] = sum;
  __syncthreads();
  for (int off = 1; off < SCAN_BLOCK; off <<= 1) {
    unsigned t = (threadIdx.x >= (unsigned)off) ? lds[threadIdx.x - off] : 0u;
    __syncthreads();
    lds[threadIdx.x] += t;
    __syncthreads();
  }
  unsigned threadExcl = lds[threadIdx.x] - sum;
  for (int i = 0; i < SCAN_ITEMS; ++i) {
    int idx = tbase + i;
    if (idx < n) out[idx] = threadExcl + vals[i];
  }
  if (threadIdx.x == SCAN_BLOCK - 1) chunkSums[blockIdx.x] = lds[SCAN_BLOCK - 1];
}

__global__ void scanB(unsigned* chunkSums, unsigned* totalDst, int nchunks) {
  __shared__ unsigned lds[1024];
  unsigned v = (threadIdx.x < (unsigned)nchunks) ? chunkSums[threadIdx.x] : 0u;
  lds[threadIdx.x] = v;
  __syncthreads();
  for (int off = 1; off < 1024; off <<= 1) {
    unsigned t = (threadIdx.x >= (unsigned)off) ? lds[threadIdx.x - off] : 0u;
    __syncthreads();
    lds[threadIdx.x] += t;
    __syncthreads();
  }
  if (threadIdx.x < (unsigned)nchunks) chunkSums[threadIdx.x] = lds[threadIdx.x] - v;
  if (threadIdx.x == 0 && totalDst) *totalDst = lds[1023];
}

__global__ void scanC(unsigned* __restrict__ out, unsigned* __restrict__ out2,
                      const unsigned* __restrict__ chunkSums, int n) {
  int idx = blockIdx.x * blockDim.x + threadIdx.x;
  if (idx >= n) return;
  unsigned v = out[idx] + chunkSums[idx / SCAN_CHUNK];
  out[idx] = v;
  if (out2) out2[idx] = v;
}

// ---- build rank -> key map ----
__global__ void k_ukey(const unsigned* __restrict__ cnt, const unsigned* __restrict__ rank,
                       unsigned* __restrict__ ukeyArr) {
  int k = blockIdx.x * blockDim.x + threadIdx.x;
  if (k >= KSP) return;
  if (cnt[k]) ukeyArr[rank[k]] = (unsigned)k;
}

// ---- per-point: inv index + pos accumulation into d_out ----
__global__ void k_inv_pos(const unsigned* __restrict__ key, const unsigned* __restrict__ rank,
                          unsigned* __restrict__ inv, const float* __restrict__ pos,
                          float* __restrict__ out, const unsigned* __restrict__ hdr, int N) {
  int i = blockIdx.x * blockDim.x + threadIdx.x;
  if (i >= N) return;
  unsigned m = rank[key[i]];
  inv[i] = m;
  unsigned M = hdr[3];
  unsigned long long O1 = 64ull * M;
  atomicAdd(&out[O1 + 3ull * m + 0], pos[3 * i + 0]);
  atomicAdd(&out[O1 + 3ull * m + 1], pos[3 * i + 1]);
  atomicAdd(&out[O1 + 3ull * m + 2], pos[3 * i + 2]);
}

// ---- per-(point,feature): encoded atomic max into d_out[0 .. M*64) ----
__global__ void k_xmax(const float* __restrict__ x, const unsigned* __restrict__ inv,
                       float* __restrict__ out, long long total) {
  long long t = (long long)blockIdx.x * blockDim.x + threadIdx.x;
  if (t >= total) return;
  int i = (int)(t >> 6);
  int d = (int)(t & 63);
  unsigned m = inv[i];
  unsigned e = encF(x[t]);
  atomicMax((unsigned*)&out[(unsigned long long)m * 64u + d], e);
}

// ---- decode pooled_x in place ----
__global__ void k_decode(float* __restrict__ out, const unsigned* __restrict__ hdr) {
  long long idx = (long long)blockIdx.x * blockDim.x + threadIdx.x;
  unsigned M = hdr[3];
  if (idx >= (long long)M * 64) return;
  unsigned u = __float_as_uint(out[idx]);
  out[idx] = decF(u);
}

// ---- pos mean: divide by counts ----
__global__ void k_posdiv(float* __restrict__ out, const unsigned* __restrict__ hdr,
                         const unsigned* __restrict__ ukeyArr, const unsigned* __restrict__ cnt) {
  int m = blockIdx.x * blockDim.x + threadIdx.x;
  unsigned M = hdr[3];
  if ((unsigned)m >= M) return;
  float c = (float)cnt[ukeyArr[m]];
  unsigned long long O1 = 64ull * M;
  out[O1 + 3ull * m + 0] /= c;
  out[O1 + 3ull * m + 1] /= c;
  out[O1 + 3ull * m + 2] /= c;
}

// ---- edges: histogram by src voxel ----
__global__ void k_ehist(const int* __restrict__ ei, const unsigned* __restrict__ inv,
                        unsigned* __restrict__ bucketCnt, int E) {
  int e = blockIdx.x * blockDim.x + threadIdx.x;
  if (e >= E) return;
  unsigned a = inv[ei[2 * e]];
  unsigned b = inv[ei[2 * e + 1]];
  if (a != b) atomicAdd(&bucketCnt[a], 1u);
}

// ---- edges: scatter dst into buckets ----
__global__ void k_escatter(const int* __restrict__ ei, const unsigned* __restrict__ inv,
                           unsigned* __restrict__ cursor, unsigned* __restrict__ edgeVal, int E) {
  int e = blockIdx.x * blockDim.x + threadIdx.x;
  if (e >= E) return;
  unsigned a = inv[ei[2 * e]];
  unsigned b = inv[ei[2 * e + 1]];
  if (a != b) {
    unsigned p = atomicAdd(&cursor[a], 1u);
    edgeVal[p] = b;
  }
}

// ---- per-bucket: insertion sort + distinct count ----
__global__ void k_sort(unsigned* __restrict__ edgeVal, const unsigned* __restrict__ bucketStart,
                       const unsigned* __restrict__ bucketCnt, unsigned* __restrict__ distinctCnt,
                       const unsigned* __restrict__ hdr) {
  unsigned u = blockIdx.x * blockDim.x + threadIdx.x;
  unsigned M = hdr[3];
  if (u >= M) return;
  unsigned s = bucketStart[u], c = bucketCnt[u];
  for (unsigned i = 1; i < c; ++i) {
    unsigned v = edgeVal[s + i];
    int j = (int)i - 1;
    while (j >= 0 && edgeVal[s + j] > v) {
      edgeVal[s + j + 1] = edgeVal[s + j];
      --j;
    }
    edgeVal[s + j + 1] = v;
  }
  unsigned d = 0, prev = 0xFFFFFFFFu;
  for (unsigned i = 0; i < c; ++i) {
    unsigned v = edgeVal[s + i];
    if (i == 0 || v != prev) ++d;
    prev = v;
  }
  distinctCnt[u] = d;
}

// ---- per-bucket: write deduped edges as floats ----
__global__ void k_ewrite(const unsigned* __restrict__ edgeVal, const unsigned* __restrict__ bucketStart,
                         const unsigned* __restrict__ bucketCnt, const unsigned* __restrict__ outStart,
                         const unsigned* __restrict__ hdr, float* __restrict__ out) {
  unsigned u = blockIdx.x * blockDim.x + threadIdx.x;
  unsigned M = hdr[3];
  if (u >= M) return;
  unsigned s = bucketStart[u], c = bucketCnt[u], o = outStart[u];
  unsigned long long O2 = 67ull * M;
  unsigned j = 0, prev = 0xFFFFFFFFu;
  float fu = (float)u;
  for (unsigned i = 0; i < c; ++i) {
    unsigned v = edgeVal[s + i];
    if (i == 0 || v != prev) {
      unsigned long long row = o + j;
      out[O2 + 2 * row + 0] = fu;
      out[O2 + 2 * row + 1] = (float)v;
      ++j;
    }
    prev = v;
  }
}

// ---- self loops + new_batch ----
__global__ void k_final(const unsigned* __restrict__ ukeyArr, const unsigned* __restrict__ hdr,
                        float* __restrict__ out) {
  unsigned m = blockIdx.x * blockDim.x + threadIdx.x;
  unsigned M = hdr[3];
  if (m >= M) return;
  unsigned Ed = hdr[5];
  unsigned long long O2 = 67ull * M;
  unsigned long long row = (unsigned long long)Ed + m;
  float fm = (float)m;
  out[O2 + 2 * row + 0] = fm;
  out[O2 + 2 * row + 1] = fm;
  unsigned s0 = hdr[0] + 1, s1 = hdr[1] + 1, s2 = hdr[2] + 1;
  unsigned vol = s0 * s1 * s2;
  unsigned long long O3 = O2 + 2ull * (Ed + M);
  out[O3 + m] = (float)(ukeyArr[m] / vol);
}

extern "C" void kernel_launch(void* const* d_in, const int* in_sizes, int n_in,
                              void* d_out, int out_size, void* d_ws, size_t ws_size,
                              hipStream_t stream) {
  const float* x = (const float*)d_in[0];
  const float* pos = (const float*)d_in[1];
  const int* ei = (const int*)d_in[2];
  const int* batch = (const int*)d_in[3];
  float* out = (float*)d_out;
  int N = in_sizes[3];
  int E = in_sizes[2] / 2;

  unsigned* ws = (unsigned*)d_ws;
  // ws layout (u32 units)
  unsigned* hdr        = ws;                    // 64
  unsigned* cnt        = ws + 64;               // KSP
  unsigned* bucketCnt  = cnt + KSP;             // KSP
  unsigned* distinctCnt= bucketCnt + KSP;       // KSP
  unsigned* rank       = distinctCnt + KSP;     // KSP
  unsigned* ukeyArr    = rank + KSP;            // KSP
  unsigned* bucketStart= ukeyArr + KSP;         // KSP
  unsigned* cursor     = bucketStart + KSP;     // KSP
  unsigned* outStart   = cursor + KSP;          // KSP
  unsigned* chunkSums  = outStart + KSP;        // 1024
  unsigned* key        = chunkSums + 1024;      // N
  unsigned* inv        = key + N;               // N
  unsigned* edgeVal    = inv + N;               // E

  // zero: hdr + cnt + bucketCnt + distinctCnt (contiguous), and all of d_out
  hipMemsetAsync(ws, 0, (size_t)(64 + 3 * KSP) * 4, stream);
  hipMemsetAsync(d_out, 0, (size_t)out_size * 4, stream);

  const int B = 256;
  int gN = (N + B - 1) / B;
  int gE = (E + B - 1) / B;
  int gK = (KSP + B - 1) / B;
  long long totalX = (long long)N * 64;
  int gX = (int)((totalX + B - 1) / B);
  int gD = (int)(((long long)KSP * 64 + B - 1) / B);

  k_qmax<<<gN, B, 0, stream>>>(pos, hdr, N);
  k_keys<<<gN, B, 0, stream>>>(pos, batch, hdr, key, cnt, N);

  // rank = exclusive scan of presence(cnt); total -> hdr[3] = M
  scanA<<<NCHUNK, SCAN_BLOCK, 0, stream>>>(cnt, rank, chunkSums, KSP, 1);
  scanB<<<1, 1024, 0, stream>>>(chunkSums, &hdr[3], NCHUNK);
  scanC<<<gK, B, 0, stream>>>(rank, nullptr, chunkSums, KSP);

  k_ukey<<<gK, B, 0, stream>>>(cnt, rank, ukeyArr);
  k_inv_pos<<<gN, B, 0, stream>>>(key, rank, inv, pos, out, hdr, N);
  k_xmax<<<gX, B, 0, stream>>>(x, inv, out, totalX);
  k_decode<<<gD, B, 0, stream>>>(out, hdr);
  k_posdiv<<<gK, B, 0, stream>>>(out, hdr, ukeyArr, cnt);

  k_ehist<<<gE, B, 0, stream>>>(ei, inv, bucketCnt, E);
  scanA<<<NCHUNK, SCAN_BLOCK, 0, stream>>>(bucketCnt, bucketStart, chunkSums, KSP, 0);
  scanB<<<1, 1024, 0, stream>>>(chunkSums, &hdr[4], NCHUNK);
  scanC<<<gK, B, 0, stream>>>(bucketStart, cursor, chunkSums, KSP);
  k_escatter<<<gE, B, 0, stream>>>(ei, inv, cursor, edgeVal, E);
  k_sort<<<gK, B, 0, stream>>>(edgeVal, bucketStart, bucketCnt, distinctCnt, hdr);
  scanA<<<NCHUNK, SCAN_BLOCK, 0, stream>>>(distinctCnt, outStart, chunkSums, KSP, 0);
  scanB<<<1, 1024, 0, stream>>>(chunkSums, &hdr[5], NCHUNK);
  scanC<<<gK, B, 0, stream>>>(outStart, nullptr, chunkSums, KSP);
  k_ewrite<<<gK, B, 0, stream>>>(edgeVal, bucketStart, bucketCnt, outStart, hdr, out);
  k_final<<<gK, B, 0, stream>>>(ukeyArr, hdr, out);

  (void)n_in; (void)ws_size;
}